// Round 5
// baseline (87.349 us; speedup 1.0000x reference)
//
#include <hip/hip_runtime.h>

#define LOG2E 1.4426950408889634f
#define LN2F  0.6931471805599453f
#define RS5F  0.4472135954999579f  // 1/sqrt(5)

// single-instruction ds_swizzle (BitMode: src = ((dst & AND) | OR) ^ XOR)
template<int XOR, int OR, int AND>
__device__ __forceinline__ float swz(float v) {
    return __int_as_float(__builtin_amdgcn_ds_swizzle(
        __float_as_int(v), (XOR << 10) | (OR << 5) | AND));
}
#define SWZX(v, m)     swz<(m), 0, 0x1F>(v)      // butterfly xor within 32-half
#define BCAST16(v, s)  swz<0, (s), 0x10>(v)      // broadcast sublane s within 16-group
#define EXP2(x)  __builtin_amdgcn_exp2f(x)       // raw v_exp_f32
#define LOG2_(x) __builtin_amdgcn_logf(x)        // raw v_log_f32
#define RCP_(x)  __builtin_amdgcn_rcpf(x)        // raw v_rcp_f32

__device__ __forceinline__ float sel4(float e0, float e1, float e2, float e3, int c) {
    float lo = (c & 1) ? e1 : e0;
    float hi = (c & 1) ? e3 : e2;
    return (c & 2) ? hi : lo;
}

// 8 items per WAVE as TWO independent sets of 4 (16 lanes per item).
// Sets are interleaved in program order so their latency chains (swizzle
// reductions, softmax exp chains) overlap. Within an item's 16-lane group:
// u = lane&15, c1 = u>>2, c2 = u&3. In-lane j in [0,8): c0 = j>>2, c3 = j&3.
// A-combo = (c0,c1,c2,c3); C-combo = digit complement. Log2-domain state.
__global__ __launch_bounds__(256, 4) void mfnet_layer_kernel(
    const float* __restrict__ log_qi,   // (N,4,4)
    const float* __restrict__ G,        // (N,8,4)
    const float* __restrict__ sqrt_2rho,// (N,)
    const float* __restrict__ alpha_ptr,// (1,)
    float* __restrict__ out,            // (N,4,4)
    int N)
{
    const int tid  = threadIdx.x;
    const int wv   = tid >> 6;
    const int lane = tid & 63;
    const int grp  = lane >> 4;
    const int u    = lane & 15;
    const int ib   = blockIdx.x * 32 + wv * 8;   // wave's first item (8/wave)

    // G staging: 8 items x 32 floats, padded stride 36 (write-conflict-free).
    // Wave-local: wave wv writes AND reads only sG[wv] -> no __syncthreads
    // (same-wave DS ordering is enforced by lgkmcnt waits).
    __shared__ __align__(16) float sG[4][292];
    {
        size_t gidx = (size_t)ib * 32 + (size_t)(lane * 4);
        size_t gmax = (size_t)N * 32 - 4;
        if (gidx > gmax) gidx = gmax;
        const float4 gv = *(const float4*)(G + gidx);
        *(float4*)&sG[wv][(lane >> 3) * 36 + ((lane * 4) & 31)] = gv;
    }

    const float alpha = alpha_ptr[0];
    const float alm1  = 1.0f - alpha;
    const int c1 = u >> 2, c2 = u & 3;

    int   item[2]; bool valid[2];
    float rv[2], s1v[2], s2v[2];
    float slq2[2][16];
#pragma unroll
    for (int s = 0; s < 2; ++s) {
        int it = ib + s * 4 + grp;
        valid[s] = (it < N);
        item[s]  = valid[s] ? it : (N - 1);
        float rho = sqrt_2rho[item[s]];
        rv[s]  = rho * RS5F;
        s1v[s] = rv[s] * (float)(2 * c1 - 3);
        s2v[s] = rv[s] * (float)(2 * c2 - 3);
        const float4* lq = (const float4*)(log_qi + (size_t)item[s] * 16);
#pragma unroll
        for (int i = 0; i < 4; ++i) {
            float4 v = lq[i];
            slq2[s][4*i+0] = v.x * LOG2E; slq2[s][4*i+1] = v.y * LOG2E;
            slq2[s][4*i+2] = v.z * LOG2E; slq2[s][4*i+3] = v.w * LOG2E;
        }
    }

    // initial softmax caches (rows 1,2 selected; row 3 full)
    float q1A[2], q1C[2], q2A[2], q2C[2], q3v[2][4];
#pragma unroll
    for (int s = 0; s < 2; ++s) {
        {
            float e0 = EXP2(slq2[s][4]),  e1 = EXP2(slq2[s][5]);
            float e2 = EXP2(slq2[s][6]),  e3 = EXP2(slq2[s][7]);
            float inv = RCP_(e0 + e1 + e2 + e3);
            q1A[s] = sel4(e0, e1, e2, e3, c1) * inv;
            q1C[s] = sel4(e0, e1, e2, e3, c1 ^ 3) * inv;
        }
        {
            float e0 = EXP2(slq2[s][8]),  e1 = EXP2(slq2[s][9]);
            float e2 = EXP2(slq2[s][10]), e3 = EXP2(slq2[s][11]);
            float inv = RCP_(e0 + e1 + e2 + e3);
            q2A[s] = sel4(e0, e1, e2, e3, c2) * inv;
            q2C[s] = sel4(e0, e1, e2, e3, c2 ^ 3) * inv;
        }
        {
            float e0 = EXP2(slq2[s][12]), e1 = EXP2(slq2[s][13]);
            float e2 = EXP2(slq2[s][14]), e3 = EXP2(slq2[s][15]);
            float inv = RCP_(e0 + e1 + e2 + e3);
            q3v[s][0] = e0*inv; q3v[s][1] = e1*inv;
            q3v[s][2] = e2*inv; q3v[s][3] = e3*inv;
        }
    }

    // ---- laplace-log-cdf accumulation (log2 units); pair trick C = -A ----
    float lpA[2][8] = {{0,0,0,0,0,0,0,0},{0,0,0,0,0,0,0,0}};
    float lpC[2][8] = {{0,0,0,0,0,0,0,0},{0,0,0,0,0,0,0,0}};
    const float* gw[2] = { &sG[wv][grp * 36], &sG[wv][(4 + grp) * 36] };
#pragma unroll
    for (int r = 0; r < 8; ++r) {
#pragma unroll
        for (int s = 0; s < 2; ++s) {
            float4 g = *(const float4*)(gw[s] + r * 4);
            float b12 = fmaf(g.y, s1v[s], g.z * s2v[s]);
            float m0  = g.x * rv[s];
            float m3  = g.w * rv[s];
            float t0  = fmaf(m0, -3.0f, b12);   // c0 = 0
            float t1  = b12 - m0;               // c0 = 1
#pragma unroll
            for (int j = 0; j < 8; ++j) {
                float tb = (j & 4) ? t1 : t0;
                float w3 = (float)(2 * (j & 3) - 3);
                float x  = fmaf(m3, w3, tb);
                float tt = fabsf(x) * (-LOG2E);
                float e  = EXP2(tt);
                float lg = LOG2_(fmaf(e, -0.5f, 1.0f));
                float ng = tt - 1.0f;
                bool neg = (x < 0.0f);
                lpA[s][j] += neg ? ng : lg;
                lpC[s][j] += neg ? lg : ng;
            }
        }
    }

    // U-sums over c3 with q3 weights
    float UA0[2], UA1[2], UC2[2], UC3[2];
#pragma unroll
    for (int s = 0; s < 2; ++s) {
        UA0[s] = lpA[s][0]*q3v[s][0] + lpA[s][1]*q3v[s][1] + lpA[s][2]*q3v[s][2] + lpA[s][3]*q3v[s][3];
        UA1[s] = lpA[s][4]*q3v[s][0] + lpA[s][5]*q3v[s][1] + lpA[s][6]*q3v[s][2] + lpA[s][7]*q3v[s][3];
        UC3[s] = lpC[s][0]*q3v[s][3] + lpC[s][1]*q3v[s][2] + lpC[s][2]*q3v[s][1] + lpC[s][3]*q3v[s][0];
        UC2[s] = lpC[s][4]*q3v[s][3] + lpC[s][5]*q3v[s][2] + lpC[s][6]*q3v[s][1] + lpC[s][7]*q3v[s][0];
    }

    // ======== round 0 (groups = c0) + q0 refresh + reusable inner products ====
    float IA[2], IC[2], Pin[2][4], Qin[2][4];
#pragma unroll
    for (int s = 0; s < 2; ++s) {
        float preQ  = q1A[s] * q2A[s];
        float preQC = q1C[s] * q2C[s];
        float SA0 = UA0[s]*preQ,  SA1 = UA1[s]*preQ;
        float SC2 = UC2[s]*preQC, SC3 = UC3[s]*preQC;
        SA0 += SWZX(SA0,1); SA0 += SWZX(SA0,2); SA0 += SWZX(SA0,4); SA0 += SWZX(SA0,8);
        SA1 += SWZX(SA1,1); SA1 += SWZX(SA1,2); SA1 += SWZX(SA1,4); SA1 += SWZX(SA1,8);
        SC2 += SWZX(SC2,1); SC2 += SWZX(SC2,2); SC2 += SWZX(SC2,4); SC2 += SWZX(SC2,8);
        SC3 += SWZX(SC3,1); SC3 += SWZX(SC3,2); SC3 += SWZX(SC3,4); SC3 += SWZX(SC3,8);
        slq2[s][0] = alm1*slq2[s][0] + alpha*SA0;
        slq2[s][1] = alm1*slq2[s][1] + alpha*SA1;
        slq2[s][2] = alm1*slq2[s][2] + alpha*SC2;
        slq2[s][3] = alm1*slq2[s][3] + alpha*SC3;
#pragma unroll
        for (int t = 0; t < 4; ++t) {   // round 0 renorms ALL rows
            float m = fmaxf(fmaxf(slq2[s][4*t], slq2[s][4*t+1]),
                            fmaxf(slq2[s][4*t+2], slq2[s][4*t+3]));
            slq2[s][4*t] -= m; slq2[s][4*t+1] -= m;
            slq2[s][4*t+2] -= m; slq2[s][4*t+3] -= m;
        }
        float e0 = EXP2(slq2[s][0]), e1 = EXP2(slq2[s][1]);
        float e2 = EXP2(slq2[s][2]), e3 = EXP2(slq2[s][3]);
        float inv = RCP_(e0 + e1 + e2 + e3);
        float q0v0 = e0*inv, q0v1 = e1*inv, q0v2 = e2*inv, q0v3 = e3*inv;
        IA[s] = q0v0 * UA0[s] + q0v1 * UA1[s];
        IC[s] = q0v3 * UC3[s] + q0v2 * UC2[s];
        Pin[s][0] = lpA[s][0]*q0v0 + lpA[s][4]*q0v1;
        Pin[s][1] = lpA[s][1]*q0v0 + lpA[s][5]*q0v1;
        Pin[s][2] = lpA[s][2]*q0v0 + lpA[s][6]*q0v1;
        Pin[s][3] = lpA[s][3]*q0v0 + lpA[s][7]*q0v1;
        Qin[s][0] = lpC[s][3]*q0v3 + lpC[s][7]*q0v2;
        Qin[s][1] = lpC[s][2]*q0v3 + lpC[s][6]*q0v2;
        Qin[s][2] = lpC[s][1]*q0v3 + lpC[s][5]*q0v2;
        Qin[s][3] = lpC[s][0]*q0v3 + lpC[s][4]*q0v2;
    }

    // ======== round 1 (groups = c1 = u>>2) ========
#pragma unroll
    for (int s = 0; s < 2; ++s) {
        float SA = q2A[s] * IA[s];
        float SC = q2C[s] * IC[s];
        SA += SWZX(SA,1); SA += SWZX(SA,2);
        SC += SWZX(SC,1); SC += SWZX(SC,2);
        float T = SA + SWZX(SC, 12);          // C of subgroup 3-g -> g
        float ex0 = BCAST16(T, 0),  ex1 = BCAST16(T, 4);
        float ex2 = BCAST16(T, 8),  ex3 = BCAST16(T, 12);
        slq2[s][4] = alm1*slq2[s][4] + alpha*ex0;
        slq2[s][5] = alm1*slq2[s][5] + alpha*ex1;
        slq2[s][6] = alm1*slq2[s][6] + alpha*ex2;
        slq2[s][7] = alm1*slq2[s][7] + alpha*ex3;
        float m = fmaxf(fmaxf(slq2[s][4], slq2[s][5]), fmaxf(slq2[s][6], slq2[s][7]));
        slq2[s][4] -= m; slq2[s][5] -= m; slq2[s][6] -= m; slq2[s][7] -= m;
        float e0 = EXP2(slq2[s][4]), e1 = EXP2(slq2[s][5]);
        float e2 = EXP2(slq2[s][6]), e3 = EXP2(slq2[s][7]);
        float inv = RCP_(e0 + e1 + e2 + e3);
        q1A[s] = sel4(e0, e1, e2, e3, c1) * inv;
        q1C[s] = sel4(e0, e1, e2, e3, c1 ^ 3) * inv;
    }

    // ======== round 2 (groups = c2 = u&3) ========
#pragma unroll
    for (int s = 0; s < 2; ++s) {
        float SA = q1A[s] * IA[s];
        float SC = q1C[s] * IC[s];
        SA += SWZX(SA,4); SA += SWZX(SA,8);
        SC += SWZX(SC,4); SC += SWZX(SC,8);
        float T = SA + SWZX(SC, 3);
        float ex0 = BCAST16(T, 0), ex1 = BCAST16(T, 1);
        float ex2 = BCAST16(T, 2), ex3 = BCAST16(T, 3);
        slq2[s][8]  = alm1*slq2[s][8]  + alpha*ex0;
        slq2[s][9]  = alm1*slq2[s][9]  + alpha*ex1;
        slq2[s][10] = alm1*slq2[s][10] + alpha*ex2;
        slq2[s][11] = alm1*slq2[s][11] + alpha*ex3;
        float m = fmaxf(fmaxf(slq2[s][8], slq2[s][9]), fmaxf(slq2[s][10], slq2[s][11]));
        slq2[s][8] -= m; slq2[s][9] -= m; slq2[s][10] -= m; slq2[s][11] -= m;
        float e0 = EXP2(slq2[s][8]),  e1 = EXP2(slq2[s][9]);
        float e2 = EXP2(slq2[s][10]), e3 = EXP2(slq2[s][11]);
        float inv = RCP_(e0 + e1 + e2 + e3);
        q2A[s] = sel4(e0, e1, e2, e3, c2) * inv;
        q2C[s] = sel4(e0, e1, e2, e3, c2 ^ 3) * inv;
    }

    // ======== round 3 (groups = c3, in-lane) ========
#pragma unroll
    for (int s = 0; s < 2; ++s) {
        float preQ  = q1A[s] * q2A[s];
        float preQC = q1C[s] * q2C[s];
        float R0 = Pin[s][0]*preQ + Qin[s][0]*preQC;
        float R1 = Pin[s][1]*preQ + Qin[s][1]*preQC;
        float R2 = Pin[s][2]*preQ + Qin[s][2]*preQC;
        float R3 = Pin[s][3]*preQ + Qin[s][3]*preQC;
        R0 += SWZX(R0,1); R0 += SWZX(R0,2); R0 += SWZX(R0,4); R0 += SWZX(R0,8);
        R1 += SWZX(R1,1); R1 += SWZX(R1,2); R1 += SWZX(R1,4); R1 += SWZX(R1,8);
        R2 += SWZX(R2,1); R2 += SWZX(R2,2); R2 += SWZX(R2,4); R2 += SWZX(R2,8);
        R3 += SWZX(R3,1); R3 += SWZX(R3,2); R3 += SWZX(R3,4); R3 += SWZX(R3,8);
        slq2[s][12] = alm1*slq2[s][12] + alpha*R0;
        slq2[s][13] = alm1*slq2[s][13] + alpha*R1;
        slq2[s][14] = alm1*slq2[s][14] + alpha*R2;
        slq2[s][15] = alm1*slq2[s][15] + alpha*R3;
        float m = fmaxf(fmaxf(slq2[s][12], slq2[s][13]), fmaxf(slq2[s][14], slq2[s][15]));
        slq2[s][12] -= m; slq2[s][13] -= m; slq2[s][14] -= m; slq2[s][15] -= m;
    }

    // ---- store: sublane u writes out[item*16 + u] (row=c1, col=c2) ----
#pragma unroll
    for (int s = 0; s < 2; ++s) {
        if (valid[s]) {
            float r0 = sel4(slq2[s][0],  slq2[s][1],  slq2[s][2],  slq2[s][3],  c2);
            float r1 = sel4(slq2[s][4],  slq2[s][5],  slq2[s][6],  slq2[s][7],  c2);
            float r2 = sel4(slq2[s][8],  slq2[s][9],  slq2[s][10], slq2[s][11], c2);
            float r3 = sel4(slq2[s][12], slq2[s][13], slq2[s][14], slq2[s][15], c2);
            float vv = sel4(r0, r1, r2, r3, c1);
            out[(size_t)item[s] * 16 + u] = vv * LN2F;
        }
    }
}

extern "C" void kernel_launch(void* const* d_in, const int* in_sizes, int n_in,
                              void* d_out, int out_size, void* d_ws, size_t ws_size,
                              hipStream_t stream) {
    const float* log_qi = (const float*)d_in[0];
    const float* G      = (const float*)d_in[1];
    const float* rho    = (const float*)d_in[2];
    // d_in[3] = n_var — unused by the reference
    const float* alpha  = (const float*)d_in[4];
    float* out = (float*)d_out;

    const int N = in_sizes[2];                 // 32768 batch items
    const int blocks = (N + 31) / 32;          // 32 items per block (8 per wave)
    mfnet_layer_kernel<<<blocks, 256, 0, stream>>>(log_qi, G, rho, alpha, out, N);
}

// Round 6
// 84.628 us; speedup vs baseline: 1.0322x; 1.0322x over previous
//
#include <hip/hip_runtime.h>

#define LOG2E 1.4426950408889634f
#define LN2F  0.6931471805599453f
#define RS5F  0.4472135954999579f  // 1/sqrt(5)

// single-instruction ds_swizzle (BitMode: src = ((lane & AND) | OR) ^ XOR, within 32-lane groups)
template<int XOR, int OR, int AND>
__device__ __forceinline__ float swz(float v) {
    return __int_as_float(__builtin_amdgcn_ds_swizzle(
        __float_as_int(v), (XOR << 10) | (OR << 5) | AND));
}
#define SWZX(v, m)    swz<(m), 0, 0x1F>(v)   // xor-butterfly within 32-lane item group
#define BCAST32(v, s) swz<0, (s), 0>(v)      // broadcast lane s of the 32-lane item group
#define EXP2(x)  __builtin_amdgcn_exp2f(x)   // raw v_exp_f32
#define LOG2_(x) __builtin_amdgcn_logf(x)    // raw v_log_f32
#define RCP_(x)  __builtin_amdgcn_rcpf(x)    // raw v_rcp_f32

__device__ __forceinline__ float sel4(float e0, float e1, float e2, float e3, int c) {
    float lo = (c & 1) ? e1 : e0;
    float hi = (c & 1) ? e3 : e2;
    return (c & 2) ? hi : lo;
}

// 2 items per WAVE (32 lanes per item, 8 items per 256-thread block), single
// instruction stream. Item lane index u = lane&31; digit layout:
//   bit0 = c0 (A-side c0 in {0,1}; C-complement covers {3,2})
//   bits1-2 = c2, bits3-4 = c1, c3 = in-lane j (A), c3' = 3-j (C).
// 32 lanes x 4 j x {A,C} = 256 combos. All swizzle reductions are item-local
// (BitMode spans exactly 32 lanes). Log2-domain state. VGPR target <= 64 so 8
// waves/SIMD stay resident (the round-5 kernels sat at 4 and were latency-bound).
__global__ __launch_bounds__(256, 8) void mfnet_layer_kernel(
    const float* __restrict__ log_qi,   // (N,4,4)
    const float* __restrict__ G,        // (N,8,4)
    const float* __restrict__ sqrt_2rho,// (N,)
    const float* __restrict__ alpha_ptr,// (1,)
    float* __restrict__ out,            // (N,4,4)
    int N)
{
    const int tid  = threadIdx.x;
    const int wv   = tid >> 6;
    const int lane = tid & 63;
    const int grp  = lane >> 5;          // item within wave (0/1)
    const int u    = lane & 31;
    const int ib   = blockIdx.x * 8 + wv * 2;

    // G staging: 2 items x 32 floats per wave; write stride-1 (2-way aliasing is
    // free), reads are 32-lane broadcasts. Wave-local -> no __syncthreads.
    __shared__ __align__(16) float sG[4][64];
    {
        size_t gidx = (size_t)ib * 32 + (size_t)lane;
        size_t gmax = (size_t)N * 32 - 1;
        if (gidx > gmax) gidx = gmax;
        sG[wv][lane] = G[gidx];
    }

    const int it0   = ib + grp;
    const bool valid = (it0 < N);
    const int item  = valid ? it0 : (N - 1);

    const float alpha = alpha_ptr[0];
    const float alm1  = 1.0f - alpha;

    const int bit0 = u & 1;
    const int c2   = (u >> 1) & 3;
    const int c1   = (u >> 3) & 3;

    const float rho = sqrt_2rho[item];
    const float rv  = rho * RS5F;
    const float s1  = rv * (float)(2 * c1 - 3);
    const float s2  = rv * (float)(2 * c2 - 3);
    const float w0  = rv * (float)(2 * bit0 - 3);   // c0 = bit0 -> sym -3 or -1

    // state in log2 units, replicated across the item's 32 lanes
    float slq2[16];
    {
        const float4* lq = (const float4*)(log_qi + (size_t)item * 16);
#pragma unroll
        for (int i = 0; i < 4; ++i) {
            float4 v = lq[i];
            slq2[4*i+0] = v.x * LOG2E; slq2[4*i+1] = v.y * LOG2E;
            slq2[4*i+2] = v.z * LOG2E; slq2[4*i+3] = v.w * LOG2E;
        }
    }

    // initial softmax caches: rows 1,2 (selected), row 3 (full)
    float q1A, q1C, q2A, q2C, q3v0, q3v1, q3v2, q3v3;
    {
        float e0 = EXP2(slq2[4]),  e1 = EXP2(slq2[5]);
        float e2 = EXP2(slq2[6]),  e3 = EXP2(slq2[7]);
        float inv = RCP_(e0 + e1 + e2 + e3);
        q1A = sel4(e0, e1, e2, e3, c1) * inv;
        q1C = sel4(e0, e1, e2, e3, c1 ^ 3) * inv;
    }
    {
        float e0 = EXP2(slq2[8]),  e1 = EXP2(slq2[9]);
        float e2 = EXP2(slq2[10]), e3 = EXP2(slq2[11]);
        float inv = RCP_(e0 + e1 + e2 + e3);
        q2A = sel4(e0, e1, e2, e3, c2) * inv;
        q2C = sel4(e0, e1, e2, e3, c2 ^ 3) * inv;
    }
    {
        float e0 = EXP2(slq2[12]), e1 = EXP2(slq2[13]);
        float e2 = EXP2(slq2[14]), e3 = EXP2(slq2[15]);
        float inv = RCP_(e0 + e1 + e2 + e3);
        q3v0 = e0*inv; q3v1 = e1*inv; q3v2 = e2*inv; q3v3 = e3*inv;
    }

    // ---- laplace-log-cdf accumulation (log2 units); pair trick C = -A ----
    float lpA[4] = {0,0,0,0};
    float lpC[4] = {0,0,0,0};
    const float* gw = &sG[wv][grp * 32];
#pragma unroll
    for (int r = 0; r < 8; ++r) {
        float4 g = *(const float4*)(gw + r * 4);
        float tb = fmaf(g.x, w0, fmaf(g.y, s1, g.z * s2));
        float m3 = g.w * rv;
#pragma unroll
        for (int j = 0; j < 4; ++j) {
            float w3 = (float)(2 * j - 3);          // -3,-1,1,3
            float x  = fmaf(m3, w3, tb);
            float tt = fabsf(x) * (-LOG2E);
            float e  = EXP2(tt);
            float lg = LOG2_(fmaf(e, -0.5f, 1.0f));
            float ng = tt - 1.0f;
            bool neg = (x < 0.0f);
            lpA[j] += neg ? ng : lg;
            lpC[j] += neg ? lg : ng;
        }
    }

    // U-sums over c3 with q3 weights (C-side combo c3' = 3-j)
    float UA = lpA[0]*q3v0 + lpA[1]*q3v1 + lpA[2]*q3v2 + lpA[3]*q3v3;
    float UC = lpC[0]*q3v3 + lpC[1]*q3v2 + lpC[2]*q3v1 + lpC[3]*q3v0;

    // ======== round 0 (groups = c0 = bit0 / complement) ========
    float q0A, q0C, IA, IC;
    {
        float SA = UA * (q1A * q2A);
        float SC = UC * (q1C * q2C);
        SA += SWZX(SA,2); SA += SWZX(SA,4); SA += SWZX(SA,8); SA += SWZX(SA,16);
        SC += SWZX(SC,2); SC += SWZX(SC,4); SC += SWZX(SC,8); SC += SWZX(SC,16);
        float SAo = SWZX(SA,1), SCo = SWZX(SC,1);
        float ex0 = bit0 ? SAo : SA;    // c0=0 lives at bit0=0
        float ex1 = bit0 ? SA  : SAo;
        float ex2 = bit0 ? SC  : SCo;   // c0'=2 lives at bit0=1
        float ex3 = bit0 ? SCo : SC;    // c0'=3 lives at bit0=0
        slq2[0] = alm1*slq2[0] + alpha*ex0;
        slq2[1] = alm1*slq2[1] + alpha*ex1;
        slq2[2] = alm1*slq2[2] + alpha*ex2;
        slq2[3] = alm1*slq2[3] + alpha*ex3;
#pragma unroll
        for (int t = 0; t < 4; ++t) {   // round 0 renorms ALL rows
            float m = fmaxf(fmaxf(slq2[4*t], slq2[4*t+1]),
                            fmaxf(slq2[4*t+2], slq2[4*t+3]));
            slq2[4*t] -= m; slq2[4*t+1] -= m;
            slq2[4*t+2] -= m; slq2[4*t+3] -= m;
        }
        float e0 = EXP2(slq2[0]), e1 = EXP2(slq2[1]);
        float e2 = EXP2(slq2[2]), e3 = EXP2(slq2[3]);
        float inv = RCP_(e0 + e1 + e2 + e3);
        q0A = (bit0 ? e1 : e0) * inv;   // q0[c0 = bit0]
        q0C = (bit0 ? e2 : e3) * inv;   // q0[3 - bit0]
        IA = q0A * UA;                  // valid rounds 1-2 (q0 fixed, q3 never changes)
        IC = q0C * UC;
    }

    // ======== round 1 (groups = c1 = bits3-4) ========
    {
        float SA = q2A * IA;
        float SC = q2C * IC;
        SA += SWZX(SA,1); SA += SWZX(SA,2); SA += SWZX(SA,4);   // sum c0,c2
        SC += SWZX(SC,1); SC += SWZX(SC,2); SC += SWZX(SC,4);
        float T = SA + SWZX(SC, 24);    // C of group 3-g -> g (flip bits 3-4)
        float ex0 = BCAST32(T, 0),  ex1 = BCAST32(T, 8);
        float ex2 = BCAST32(T, 16), ex3 = BCAST32(T, 24);
        slq2[4] = alm1*slq2[4] + alpha*ex0;
        slq2[5] = alm1*slq2[5] + alpha*ex1;
        slq2[6] = alm1*slq2[6] + alpha*ex2;
        slq2[7] = alm1*slq2[7] + alpha*ex3;
        float m = fmaxf(fmaxf(slq2[4], slq2[5]), fmaxf(slq2[6], slq2[7]));
        slq2[4] -= m; slq2[5] -= m; slq2[6] -= m; slq2[7] -= m;
        float e0 = EXP2(slq2[4]), e1 = EXP2(slq2[5]);
        float e2 = EXP2(slq2[6]), e3 = EXP2(slq2[7]);
        float inv = RCP_(e0 + e1 + e2 + e3);
        q1A = sel4(e0, e1, e2, e3, c1) * inv;
        q1C = sel4(e0, e1, e2, e3, c1 ^ 3) * inv;
    }

    // ======== round 2 (groups = c2 = bits1-2) ========
    {
        float SA = q1A * IA;
        float SC = q1C * IC;
        SA += SWZX(SA,1); SA += SWZX(SA,8); SA += SWZX(SA,16);  // sum c0,c1
        SC += SWZX(SC,1); SC += SWZX(SC,8); SC += SWZX(SC,16);
        float T = SA + SWZX(SC, 6);     // flip bits 1-2
        float ex0 = BCAST32(T, 0), ex1 = BCAST32(T, 2);
        float ex2 = BCAST32(T, 4), ex3 = BCAST32(T, 6);
        slq2[8]  = alm1*slq2[8]  + alpha*ex0;
        slq2[9]  = alm1*slq2[9]  + alpha*ex1;
        slq2[10] = alm1*slq2[10] + alpha*ex2;
        slq2[11] = alm1*slq2[11] + alpha*ex3;
        float m = fmaxf(fmaxf(slq2[8], slq2[9]), fmaxf(slq2[10], slq2[11]));
        slq2[8] -= m; slq2[9] -= m; slq2[10] -= m; slq2[11] -= m;
        float e0 = EXP2(slq2[8]),  e1 = EXP2(slq2[9]);
        float e2 = EXP2(slq2[10]), e3 = EXP2(slq2[11]);
        float inv = RCP_(e0 + e1 + e2 + e3);
        q2A = sel4(e0, e1, e2, e3, c2) * inv;
        q2C = sel4(e0, e1, e2, e3, c2 ^ 3) * inv;
    }

    // ======== round 3 (groups = c3, in-lane) ========
    {
        float WA = q0A * q1A * q2A;     // post-refresh rows 1,2
        float WC = q0C * q1C * q2C;
        float R0 = lpA[0]*WA + lpC[3]*WC;   // C combo with c3'=0 is j=3
        float R1 = lpA[1]*WA + lpC[2]*WC;
        float R2 = lpA[2]*WA + lpC[1]*WC;
        float R3 = lpA[3]*WA + lpC[0]*WC;
        R0 += SWZX(R0,1); R0 += SWZX(R0,2); R0 += SWZX(R0,4); R0 += SWZX(R0,8); R0 += SWZX(R0,16);
        R1 += SWZX(R1,1); R1 += SWZX(R1,2); R1 += SWZX(R1,4); R1 += SWZX(R1,8); R1 += SWZX(R1,16);
        R2 += SWZX(R2,1); R2 += SWZX(R2,2); R2 += SWZX(R2,4); R2 += SWZX(R2,8); R2 += SWZX(R2,16);
        R3 += SWZX(R3,1); R3 += SWZX(R3,2); R3 += SWZX(R3,4); R3 += SWZX(R3,8); R3 += SWZX(R3,16);
        slq2[12] = alm1*slq2[12] + alpha*R0;
        slq2[13] = alm1*slq2[13] + alpha*R1;
        slq2[14] = alm1*slq2[14] + alpha*R2;
        slq2[15] = alm1*slq2[15] + alpha*R3;
        float m = fmaxf(fmaxf(slq2[12], slq2[13]), fmaxf(slq2[14], slq2[15]));
        slq2[12] -= m; slq2[13] -= m; slq2[14] -= m; slq2[15] -= m;
    }

    // ---- store: sublanes u<16 write out[item*16 + u] (row=u>>2, col=u&3) ----
    if (valid && u < 16) {
        const int c = u & 3;
        float r0 = sel4(slq2[0],  slq2[1],  slq2[2],  slq2[3],  c);
        float r1 = sel4(slq2[4],  slq2[5],  slq2[6],  slq2[7],  c);
        float r2 = sel4(slq2[8],  slq2[9],  slq2[10], slq2[11], c);
        float r3 = sel4(slq2[12], slq2[13], slq2[14], slq2[15], c);
        float vv = sel4(r0, r1, r2, r3, u >> 2);
        out[(size_t)item * 16 + u] = vv * LN2F;
    }
}

extern "C" void kernel_launch(void* const* d_in, const int* in_sizes, int n_in,
                              void* d_out, int out_size, void* d_ws, size_t ws_size,
                              hipStream_t stream) {
    const float* log_qi = (const float*)d_in[0];
    const float* G      = (const float*)d_in[1];
    const float* rho    = (const float*)d_in[2];
    // d_in[3] = n_var — unused by the reference
    const float* alpha  = (const float*)d_in[4];
    float* out = (float*)d_out;

    const int N = in_sizes[2];                 // 32768 batch items
    const int blocks = (N + 7) / 8;            // 8 items per block (2 per wave)
    mfnet_layer_kernel<<<blocks, 256, 0, stream>>>(log_qi, G, rho, alpha, out, N);
}

// Round 7
// 79.381 us; speedup vs baseline: 1.1004x; 1.0661x over previous
//
#include <hip/hip_runtime.h>

#define LOG2E 1.4426950408889634f
#define LN2F  0.6931471805599453f
#define RS5F  0.4472135954999579f  // 1/sqrt(5)

// single-instruction ds_swizzle (BitMode: src = ((lane & AND) | OR) ^ XOR, 32-lane groups)
template<int XOR, int OR, int AND>
__device__ __forceinline__ float swz(float v) {
    return __int_as_float(__builtin_amdgcn_ds_swizzle(
        __float_as_int(v), (XOR << 10) | (OR << 5) | AND));
}
#define SWZX(v, m) swz<(m), 0, 0x1F>(v)      // xor-butterfly within 32-lane item group
#define EXP2(x)  __builtin_amdgcn_exp2f(x)   // raw v_exp_f32
#define LOG2_(x) __builtin_amdgcn_logf(x)    // raw v_log_f32
#define RCP_(x)  __builtin_amdgcn_rcpf(x)    // raw v_rcp_f32

__device__ __forceinline__ float bperm(int byte_addr, float v) {
    return __int_as_float(__builtin_amdgcn_ds_bpermute(byte_addr, __float_as_int(v)));
}

__device__ __forceinline__ float sel4(float e0, float e1, float e2, float e3, int c) {
    float lo = (c & 1) ? e1 : e0;
    float hi = (c & 1) ? e3 : e2;
    return (c & 2) ? hi : lo;
}

// 2 items per WAVE (32 lanes per item, 8 per 256-block). Combo layout as R6:
//   u = lane&31; bit0 = c0A (A in {0,1}; C complement covers {3,2});
//   bits1-2 = c2, bits3-4 = c1; in-lane j in [0,4) = c3A (C: 3-j).
// NEW: 4x4 state is DISTRIBUTED, not replicated: lane ue=u&15 holds slq entry ue
// (row=ue>>2, col=ue&3); lanes 16-31 carry an identical mirror (all state ops are
// uniform within 4-lane packs). Renorm-all = 2 swizzle-max; softmax-all = 1 exp;
// combo-space q-weights fetched via ds_bpermute with precomputed addresses.
// Deferred-renorm: subtract each row's initial max at load; afterwards every
// non-updated row has max exactly 0, so per-round renorm-all is exact.
__global__ __launch_bounds__(256, 8) void mfnet_layer_kernel(
    const float* __restrict__ log_qi,   // (N,4,4)
    const float* __restrict__ G,        // (N,8,4)
    const float* __restrict__ sqrt_2rho,// (N,)
    const float* __restrict__ alpha_ptr,// (1,)
    float* __restrict__ out,            // (N,4,4)
    int N)
{
    const int tid  = threadIdx.x;
    const int wv   = tid >> 6;
    const int lane = tid & 63;
    const int grp  = lane >> 5;          // item within wave
    const int u    = lane & 31;
    const int ib   = blockIdx.x * 8 + wv * 2;

    // G staging: 2 items x 32 floats per wave, stride-1 (2-way aliasing free).
    // Wave-local -> no __syncthreads (same-wave DS ordering via lgkmcnt).
    __shared__ __align__(16) float sG[4][64];
    {
        size_t gidx = (size_t)ib * 32 + (size_t)lane;
        size_t gmax = (size_t)N * 32 - 1;
        if (gidx > gmax) gidx = gmax;
        sG[wv][lane] = G[gidx];
    }

    const int it0   = ib + grp;
    const bool valid = (it0 < N);
    const int item  = valid ? it0 : (N - 1);

    const float alpha = alpha_ptr[0];
    const float alm1  = 1.0f - alpha;

    const int bit0 = u & 1;
    const int c2   = (u >> 1) & 3;
    const int c1   = (u >> 3) & 3;
    const int ue   = u & 15;             // state-entry index (mirrored for u>=16)
    const int row  = ue >> 2;
    const int col  = ue & 3;

    // symbols with LOG2E folded in (whole laplace pipeline in log2 units)
    const float rv = sqrt_2rho[item] * (RS5F * LOG2E);
    const float s1 = rv * (float)(2 * c1 - 3);
    const float s2 = rv * (float)(2 * c2 - 3);
    const float w0 = rv * (float)(2 * bit0 - 3);

    // distributed state (log2 units), init + deferred renorm (row max -> 0)
    float slqD = log_qi[(size_t)item * 16 + ue] * LOG2E;
    {
        float m1 = fmaxf(slqD, SWZX(slqD, 1));
        float m  = fmaxf(m1, SWZX(m1, 2));
        slqD -= m;
    }

    // softmax over all rows at once: qD[lane ue] = q_row(col)
    auto softmax_all = [&](float s) {
        float e = EXP2(s);
        float t = e + SWZX(e, 1);
        float den = t + SWZX(t, 2);
        return e * RCP_(den);
    };
    float qD = softmax_all(slqD);

    // persistent bpermute addresses (byte addr = 4 * wave lane; gbase = 32*grp)
    const int gbase = lane & 32;
    const int aQ1A = (gbase + 4 + c1) << 2;
    const int aQ1C = (gbase + 4 + (c1 ^ 3)) << 2;
    const int aQ2A = (gbase + 8 + c2) << 2;
    const int aQ2C = (gbase + 8 + (c2 ^ 3)) << 2;
    const int aR1  = (gbase + (col << 3)) << 2;   // a lane whose c1 == col
    const int aR2  = (gbase + (col << 1)) << 2;   // a lane whose c2 == col

    float q1A = bperm(aQ1A, qD), q1C = bperm(aQ1C, qD);
    float q2A = bperm(aQ2A, qD), q2C = bperm(aQ2C, qD);
    const int a3 = (gbase + 12) << 2;
    float q3v0 = bperm(a3, qD),      q3v1 = bperm(a3 + 4, qD);
    float q3v2 = bperm(a3 + 8, qD),  q3v3 = bperm(a3 + 12, qD);

    // ---- laplace-log-cdf accumulation (log2 units); pair trick C = -A ----
    float lpA[4] = {0, 0, 0, 0};
    float lpC[4] = {0, 0, 0, 0};
    const float* gw = &sG[wv][grp * 32];
#pragma unroll
    for (int r = 0; r < 8; ++r) {
        float4 g = *(const float4*)(gw + r * 4);
        float tb = fmaf(g.x, w0, fmaf(g.y, s1, g.z * s2));
        float m3 = g.w * rv;
#pragma unroll
        for (int j = 0; j < 4; ++j) {
            float t  = fmaf(m3, (float)(2 * j - 3), tb);   // x*LOG2E
            float at = -fabsf(t);                          // folds into modifiers
            float e  = EXP2(at);
            float lg = LOG2_(fmaf(e, -0.5f, 1.0f));
            float ng = at - 1.0f;
            bool neg = (t < 0.0f);
            lpA[j] += neg ? ng : lg;
            lpC[j] += neg ? lg : ng;
        }
    }

    // U-sums over c3 with q3 weights (C combo c3' = 3-j)
    float UA = lpA[0]*q3v0 + lpA[1]*q3v1 + lpA[2]*q3v2 + lpA[3]*q3v3;
    float UC = lpC[0]*q3v3 + lpC[1]*q3v2 + lpC[2]*q3v1 + lpC[3]*q3v0;

    // ======== round 0 (groups = c0) ========
    float q0A, q0C, IA, IC;
    {
        float SA = UA * (q1A * q2A);
        float SC = UC * (q1C * q2C);
        SA += SWZX(SA,2); SA += SWZX(SA,4); SA += SWZX(SA,8); SA += SWZX(SA,16);
        SC += SWZX(SC,2); SC += SWZX(SC,4); SC += SWZX(SC,8); SC += SWZX(SC,16);
        float SAo = SWZX(SA, 1), SCo = SWZX(SC, 1);
        float A0 = bit0 ? SAo : SA;   // SA at bit0=0 -> ex(col=0)
        float A1 = bit0 ? SA  : SAo;  // ex(1)
        float C1 = bit0 ? SC  : SCo;  // ex(2) (C combos c0'=2 at bit0=1)
        float C0 = bit0 ? SCo : SC;   // ex(3)
        float exD = sel4(A0, A1, C1, C0, col);
        float bl = fmaf(alm1, slqD, alpha * exD);
        slqD = (row == 0) ? bl : slqD;
        float m1 = fmaxf(slqD, SWZX(slqD, 1));
        float m  = fmaxf(m1, SWZX(m1, 2));
        slqD -= m;
        qD = softmax_all(slqD);
        q0A = bperm((gbase + bit0) << 2, qD);
        q0C = bperm((gbase + (bit0 ^ 3)) << 2, qD);
        IA = q0A * UA;   // reusable in rounds 1-2 (q0 fixed, q3 never changes)
        IC = q0C * UC;
    }

    // ======== round 1 (groups = c1 = bits3-4) ========
    {
        float SA = q2A * IA, SC = q2C * IC;
        SA += SWZX(SA,1); SA += SWZX(SA,2); SA += SWZX(SA,4);
        SC += SWZX(SC,1); SC += SWZX(SC,2); SC += SWZX(SC,4);
        float T = SA + SWZX(SC, 24);       // C of group g^3 -> g (flip bits 3-4)
        float exD = bperm(aR1, T);         // fetch ex(col) for my state entry
        float bl = fmaf(alm1, slqD, alpha * exD);
        slqD = (row == 1) ? bl : slqD;
        float m1 = fmaxf(slqD, SWZX(slqD, 1));
        float m  = fmaxf(m1, SWZX(m1, 2));
        slqD -= m;
        qD = softmax_all(slqD);
        q1A = bperm(aQ1A, qD); q1C = bperm(aQ1C, qD);
    }

    // ======== round 2 (groups = c2 = bits1-2) ========
    {
        float SA = q1A * IA, SC = q1C * IC;
        SA += SWZX(SA,1); SA += SWZX(SA,8); SA += SWZX(SA,16);
        SC += SWZX(SC,1); SC += SWZX(SC,8); SC += SWZX(SC,16);
        float T = SA + SWZX(SC, 6);        // flip bits 1-2
        float exD = bperm(aR2, T);
        float bl = fmaf(alm1, slqD, alpha * exD);
        slqD = (row == 2) ? bl : slqD;
        float m1 = fmaxf(slqD, SWZX(slqD, 1));
        float m  = fmaxf(m1, SWZX(m1, 2));
        slqD -= m;
        qD = softmax_all(slqD);
        q2A = bperm(aQ2A, qD); q2C = bperm(aQ2C, qD);
    }

    // ======== round 3 (groups = c3, in-lane) ========
    {
        float WA = q0A * (q1A * q2A);
        float WC = q0C * (q1C * q2C);
        float R0 = lpA[0]*WA + lpC[3]*WC;  // C combo with c3'=0 is j=3
        float R1 = lpA[1]*WA + lpC[2]*WC;
        float R2 = lpA[2]*WA + lpC[1]*WC;
        float R3 = lpA[3]*WA + lpC[0]*WC;
        R0 += SWZX(R0,1); R0 += SWZX(R0,2); R0 += SWZX(R0,4); R0 += SWZX(R0,8); R0 += SWZX(R0,16);
        R1 += SWZX(R1,1); R1 += SWZX(R1,2); R1 += SWZX(R1,4); R1 += SWZX(R1,8); R1 += SWZX(R1,16);
        R2 += SWZX(R2,1); R2 += SWZX(R2,2); R2 += SWZX(R2,4); R2 += SWZX(R2,8); R2 += SWZX(R2,16);
        R3 += SWZX(R3,1); R3 += SWZX(R3,2); R3 += SWZX(R3,4); R3 += SWZX(R3,8); R3 += SWZX(R3,16);
        float exD = sel4(R0, R1, R2, R3, col);
        float bl = fmaf(alm1, slqD, alpha * exD);
        slqD = (row == 3) ? bl : slqD;
        float m1 = fmaxf(slqD, SWZX(slqD, 1));
        float m  = fmaxf(m1, SWZX(m1, 2));
        slqD -= m;
    }

    // ---- store: state lanes write their own entry directly (no sel tree) ----
    if (valid && u < 16) {
        out[(size_t)item * 16 + ue] = slqD * LN2F;
    }
}

extern "C" void kernel_launch(void* const* d_in, const int* in_sizes, int n_in,
                              void* d_out, int out_size, void* d_ws, size_t ws_size,
                              hipStream_t stream) {
    const float* log_qi = (const float*)d_in[0];
    const float* G      = (const float*)d_in[1];
    const float* rho    = (const float*)d_in[2];
    // d_in[3] = n_var — unused by the reference
    const float* alpha  = (const float*)d_in[4];
    float* out = (float*)d_out;

    const int N = in_sizes[2];                 // 32768 batch items
    const int blocks = (N + 7) / 8;            // 8 items per block (2 per wave)
    mfnet_layer_kernel<<<blocks, 256, 0, stream>>>(log_qi, G, rho, alpha, out, N);
}

// Round 8
// 76.317 us; speedup vs baseline: 1.1446x; 1.0401x over previous
//
#include <hip/hip_runtime.h>

#define LOG2E 1.4426950408889634f
#define LN2F  0.6931471805599453f
#define RS5F  0.4472135954999579f  // 1/sqrt(5)

// single-instruction ds_swizzle (BitMode: src = ((lane & AND) | OR) ^ XOR, 32-lane groups)
template<int XOR, int OR, int AND>
__device__ __forceinline__ float swz(float v) {
    return __int_as_float(__builtin_amdgcn_ds_swizzle(
        __float_as_int(v), (XOR << 10) | (OR << 5) | AND));
}
#define SWZX(v, m) swz<(m), 0, 0x1F>(v)      // xor-butterfly (bits 0-3 stay in 16-group)
#define EXP2(x)  __builtin_amdgcn_exp2f(x)   // raw v_exp_f32
#define LOG2_(x) __builtin_amdgcn_logf(x)    // raw v_log_f32
#define RCP_(x)  __builtin_amdgcn_rcpf(x)    // raw v_rcp_f32

__device__ __forceinline__ float bperm(int byte_addr, float v) {
    return __int_as_float(__builtin_amdgcn_ds_bpermute(byte_addr, __float_as_int(v)));
}

// 4 items per WAVE (16-lane item groups, 16 items per 256-block).
// Lane u = lane&15 holds state entry u (row=u>>2, col=u&3) — no mirror.
// Combo digits: c1 = u>>2 (bits 2-3), c2 = u&3 (bits 0-1); in-lane j in [0,8):
// c0A = j>>2 in {0,1}, c3A = j&3. C-combo = all-digit complement (c0C in {3,2}).
// 16 lanes x 8 j x {A,C} = 256 combos. Exactness: per-row max shifted out at
// load; NO mid-round renorms (non-updated rows have max 0, softmax is
// shift-invariant, blend inputs untouched since load); single final renorm.
__global__ __launch_bounds__(256, 7) void mfnet_layer_kernel(
    const float* __restrict__ log_qi,   // (N,4,4)
    const float* __restrict__ G,        // (N,8,4)
    const float* __restrict__ sqrt_2rho,// (N,)
    const float* __restrict__ alpha_ptr,// (1,)
    float* __restrict__ out,            // (N,4,4)
    int N)
{
    const int tid  = threadIdx.x;
    const int wv   = tid >> 6;
    const int lane = tid & 63;
    const int grp  = (lane >> 4) & 3;    // item within wave
    const int u    = lane & 15;
    const int ib   = blockIdx.x * 16 + wv * 4;

    // G staging: 4 items x 32 floats, item stride 40 (bases at banks 0/8/16/24
    // -> conflict-free 16B group-broadcast reads). Wave-local, no __syncthreads.
    __shared__ __align__(16) float sG[4][160];
    {
        size_t gidx = (size_t)ib * 32 + (size_t)(lane * 2);   // = ib*32 + 2*lane, coalesced
        size_t gmax = (size_t)N * 32 - 2;
        if (gidx > gmax) gidx = gmax;
        float2 gv = *(const float2*)(G + gidx);
        *(float2*)&sG[wv][grp * 40 + u * 2] = gv;
    }

    const int it0    = ib + grp;
    const bool valid = (it0 < N);
    const int item   = valid ? it0 : (N - 1);

    const float alpha = alpha_ptr[0];
    const float alm1  = 1.0f - alpha;

    const int col = u & 3;               // state col, also c2
    const int row = u >> 2;              // state row, also c1

    // symbols with LOG2E folded in (whole pipeline in log2 units)
    const float rv = sqrt_2rho[item] * (RS5F * LOG2E);
    const float s1 = rv * (float)(2 * row - 3);
    const float s2 = rv * (float)(2 * col - 3);

    // distributed state, log2 units; shift out each row's initial max
    float slqD = log_qi[(size_t)item * 16 + u] * LOG2E;   // addr = ib*16+lane, coalesced
    {
        float m1 = fmaxf(slqD, SWZX(slqD, 1));
        float m  = fmaxf(m1, SWZX(m1, 2));
        slqD -= m;
    }

    // softmax of all rows at once (4-lane packs)
    auto softmax_all = [&](float s) {
        float e   = EXP2(s);
        float t   = e + SWZX(e, 1);
        float den = t + SWZX(t, 2);
        return e * RCP_(den);
    };
    float qD = softmax_all(slqD);

    // bpermute byte addresses (only where the source index needs shifted lane bits)
    const int gb   = (lane & 0x30) << 2;             // group-base byte address
    const int aQ1A = gb + ((4 + row) << 2);          // q_row1[c1]
    const int aQ1C = gb + ((4 + (row ^ 3)) << 2);    // q_row1[c1^3]
    const int aR1  = gb + (col << 4);                // a lane whose c1 == col

    float q1A = bperm(aQ1A, qD), q1C = bperm(aQ1C, qD);
    float q2A  = swz<0, 8, 0x13>(qD);    // q_row2[c2]   (src = grpbit | 8 | (u&3))
    float q2C  = swz<3, 8, 0x13>(qD);    // q_row2[c2^3]
    float q3v0 = swz<0, 12, 0x10>(qD);   // q_row3[0..3] broadcast within group
    float q3v1 = swz<0, 13, 0x10>(qD);
    float q3v2 = swz<0, 14, 0x10>(qD);
    float q3v3 = swz<0, 15, 0x10>(qD);

    // ---- laplace-log-cdf accumulation (log2 units); pair trick C = -A ----
    float lpA[8] = {0,0,0,0,0,0,0,0};
    float lpC[8] = {0,0,0,0,0,0,0,0};
    const float* gw = &sG[wv][grp * 40];
#pragma unroll
    for (int r = 0; r < 8; ++r) {
        float4 g  = *(const float4*)(gw + r * 4);
        float b12 = fmaf(g.y, s1, g.z * s2);
        float m0  = g.x * rv;
        float m3  = g.w * rv;
        float t0  = fmaf(m0, -3.0f, b12);   // c0 = 0
        float t1  = b12 - m0;               // c0 = 1
#pragma unroll
        for (int j = 0; j < 8; ++j) {
            float tb = (j & 4) ? t1 : t0;
            float t  = fmaf(m3, (float)(2 * (j & 3) - 3), tb);   // x*LOG2E
            float at = -fabsf(t);
            float e  = EXP2(at);
            float lg = LOG2_(fmaf(e, -0.5f, 1.0f));
            float ng = at - 1.0f;
            bool neg = (t < 0.0f);
            lpA[j] += neg ? ng : lg;
            lpC[j] += neg ? lg : ng;
        }
    }

    // U-sums over c3 with q3 weights (C combo: c0C = 3-(j>>2), c3C = 3-(j&3))
    float UA0 = lpA[0]*q3v0 + lpA[1]*q3v1 + lpA[2]*q3v2 + lpA[3]*q3v3;
    float UA1 = lpA[4]*q3v0 + lpA[5]*q3v1 + lpA[6]*q3v2 + lpA[7]*q3v3;
    float UC3 = lpC[0]*q3v3 + lpC[1]*q3v2 + lpC[2]*q3v1 + lpC[3]*q3v0;
    float UC2 = lpC[4]*q3v3 + lpC[5]*q3v2 + lpC[6]*q3v1 + lpC[7]*q3v0;

    // ======== round 0 (groups = c0, in-lane) ========
    float JA, JC, Pin0, Pin1, Pin2, Pin3, Qin0, Qin1, Qin2, Qin3;
    {
        float preQ  = q1A * q2A;
        float preQC = q1C * q2C;
        float VA0 = UA0 * preQ,  VA1 = UA1 * preQ;    // -> ex cols 0,1
        float VC2 = UC2 * preQC, VC3 = UC3 * preQC;   // -> ex cols 2,3
        // reduce-scatter: pre-swap by bit0, then butterfly bits 1-3
        bool bb = (u & 1);
        float S01 = (bb ? VA1 : VA0) + SWZX(bb ? VA0 : VA1, 1);
        float S23 = (bb ? VC3 : VC2) + SWZX(bb ? VC2 : VC3, 1);
        S01 += SWZX(S01, 2); S01 += SWZX(S01, 4); S01 += SWZX(S01, 8);
        S23 += SWZX(S23, 2); S23 += SWZX(S23, 4); S23 += SWZX(S23, 8);
        float exD = (col & 2) ? S23 : S01;   // component parity == col&1 == bit0
        float bl = fmaf(alm1, slqD, alpha * exD);
        slqD = (row == 0) ? bl : slqD;
        qD = softmax_all(slqD);
        float q0v0 = swz<0, 0, 0x10>(qD);
        float q0v1 = swz<0, 1, 0x10>(qD);
        float q0v2 = swz<0, 2, 0x10>(qD);
        float q0v3 = swz<0, 3, 0x10>(qD);
        JA = q0v0*UA0 + q0v1*UA1;            // reusable rounds 1-2
        JC = q0v3*UC3 + q0v2*UC2;
        Pin0 = lpA[0]*q0v0 + lpA[4]*q0v1;    // round-3 A-side per c3
        Pin1 = lpA[1]*q0v0 + lpA[5]*q0v1;
        Pin2 = lpA[2]*q0v0 + lpA[6]*q0v1;
        Pin3 = lpA[3]*q0v0 + lpA[7]*q0v1;
        Qin0 = lpC[3]*q0v3 + lpC[7]*q0v2;    // C-side: c3C=c -> j&3=3-c
        Qin1 = lpC[2]*q0v3 + lpC[6]*q0v2;
        Qin2 = lpC[1]*q0v3 + lpC[5]*q0v2;
        Qin3 = lpC[0]*q0v3 + lpC[4]*q0v2;
    }

    // ======== round 1 (groups = c1 = bits 2-3) ========
    {
        float SA = q2A * JA, SC = q2C * JC;
        SA += SWZX(SA, 1); SA += SWZX(SA, 2);       // sum over c2
        SC += SWZX(SC, 1); SC += SWZX(SC, 2);
        float T = SA + SWZX(SC, 12);                // C of group c1^3 -> c1
        float exD = bperm(aR1, T);                  // ex[col]
        float bl = fmaf(alm1, slqD, alpha * exD);
        slqD = (row == 1) ? bl : slqD;
        qD = softmax_all(slqD);
        q1A = bperm(aQ1A, qD); q1C = bperm(aQ1C, qD);
    }

    // ======== round 2 (groups = c2 = bits 0-1) ========
    {
        float SA = q1A * JA, SC = q1C * JC;
        SA += SWZX(SA, 4); SA += SWZX(SA, 8);       // sum over c1
        SC += SWZX(SC, 4); SC += SWZX(SC, 8);
        float exD = SA + SWZX(SC, 3);               // lands on own lane: c2 == col
        float bl = fmaf(alm1, slqD, alpha * exD);
        slqD = (row == 2) ? bl : slqD;
        qD = softmax_all(slqD);
        q2A = swz<0, 8, 0x13>(qD);
        q2C = swz<3, 8, 0x13>(qD);
    }

    // ======== round 3 (groups = c3, in-lane) ========
    {
        float WA = q1A * q2A, WC = q1C * q2C;
        float V0 = Pin0*WA + Qin0*WC;
        float V1 = Pin1*WA + Qin1*WC;
        float V2 = Pin2*WA + Qin2*WC;
        float V3 = Pin3*WA + Qin3*WC;
        bool bb = (u & 1);
        float S01 = (bb ? V1 : V0) + SWZX(bb ? V0 : V1, 1);
        float S23 = (bb ? V3 : V2) + SWZX(bb ? V2 : V3, 1);
        S01 += SWZX(S01, 2); S01 += SWZX(S01, 4); S01 += SWZX(S01, 8);
        S23 += SWZX(S23, 2); S23 += SWZX(S23, 4); S23 += SWZX(S23, 8);
        float exD = (col & 2) ? S23 : S01;
        float bl = fmaf(alm1, slqD, alpha * exD);
        slqD = (row == 3) ? bl : slqD;
    }

    // ---- single final renorm (all rows), then coalesced store ----
    {
        float m1 = fmaxf(slqD, SWZX(slqD, 1));
        float m  = fmaxf(m1, SWZX(m1, 2));
        slqD -= m;
    }
    if (valid) {
        out[(size_t)item * 16 + u] = slqD * LN2F;   // addr = ib*16+lane, coalesced
    }
}

extern "C" void kernel_launch(void* const* d_in, const int* in_sizes, int n_in,
                              void* d_out, int out_size, void* d_ws, size_t ws_size,
                              hipStream_t stream) {
    const float* log_qi = (const float*)d_in[0];
    const float* G      = (const float*)d_in[1];
    const float* rho    = (const float*)d_in[2];
    // d_in[3] = n_var — unused by the reference
    const float* alpha  = (const float*)d_in[4];
    float* out = (float*)d_out;

    const int N = in_sizes[2];                 // 32768 batch items
    const int blocks = (N + 15) / 16;          // 16 items per block (4 per wave)
    mfnet_layer_kernel<<<blocks, 256, 0, stream>>>(log_qi, G, rho, alpha, out, N);
}